// Round 7
// baseline (741.900 us; speedup 1.0000x reference)
//
#include <hip/hip_runtime.h>

typedef __bf16 bf16;
typedef __attribute__((ext_vector_type(8))) __bf16 bf16x8;
typedef __attribute__((ext_vector_type(4))) __bf16 bf16x4;
typedef __attribute__((ext_vector_type(4))) float floatx4;

#define B_SZ 512
#define N_SZ 2048
#define DIN  784
#define DINP 800      // 784 padded to multiple of 32
#define ACT_LD 12288  // actsT row stride: 6 slices x 2048

// async global->LDS, 16B per lane (input-layer gemm only)
__device__ __forceinline__ void load_lds16(const bf16* g, bf16* l) {
    __builtin_amdgcn_global_load_lds(
        (const __attribute__((address_space(1))) void*)g,
        (__attribute__((address_space(3))) void*)l, 16, 0, 0);
}

// ---------------------------------------------------------------------------
// prep: x[512][784] -> xb[512][800] bf16 (zero pad), w_in[2048][784] -> w_inb
// ---------------------------------------------------------------------------
__global__ __launch_bounds__(256)
void prep_kernel(const float* __restrict__ x, const float* __restrict__ w_in,
                 bf16* __restrict__ xb, bf16* __restrict__ w_inb)
{
    int g = blockIdx.x * 256 + threadIdx.x;
    const int GPR = DINP / 4;                         // 200 groups per row
    const float* src; bf16* dst; int row, c;
    if (g < B_SZ * GPR) {
        row = g / GPR; c = g - row * GPR;
        src = x + (size_t)row * DIN;  dst = xb + (size_t)row * DINP;
    } else {
        int h = g - B_SZ * GPR;
        row = h / GPR; c = h - row * GPR;
        src = w_in + (size_t)row * DIN;  dst = w_inb + (size_t)row * DINP;
    }
    int k = c * 4;
    floatx4 v = (floatx4){0.f, 0.f, 0.f, 0.f};
    if (k < DIN) v = *(const floatx4*)(src + k);      // 784 % 4 == 0
    bf16x4 o;
    o[0] = (bf16)v[0]; o[1] = (bf16)v[1]; o[2] = (bf16)v[2]; o[3] = (bf16)v[3];
    *(bf16x4*)(dst + k) = o;
}

// ---------------------------------------------------------------------------
// wm_pack: WMb[jj][ntile][ktile][r6][slot] = bf16(W*M), 64x64 tiles,
// slot = cgroup ^ (r6&7)  (LDS bank swizzle baked into the global layout).
// Reads W,M perfectly sequentially (wave = 1KB contiguous per instruction) --
// this is the ONLY kernel that touches the 503 MB fp32 W/M stream.
// Writes 126 MB bf16 (fits + stays resident in 256 MB L3).
// ---------------------------------------------------------------------------
__global__ __launch_bounds__(256)
void wm_pack_kernel(const float* __restrict__ W, const float* __restrict__ M,
                    bf16* __restrict__ WMb)
{
    size_t g = (size_t)blockIdx.x * 256 + threadIdx.x;   // 7,864,320 threads
    size_t e = g << 3;                                   // 8 src elems/thread
    int jj   = (int)(e >> 22);                           // matrix (2048x2048)
    int rem  = (int)(e & 4194303);
    int r    = rem >> 11;                                // row
    int c    = rem & 2047;                               // col (multiple of 8)
    int ktile = c >> 6;
    int sg    = (c >> 3) & 7;                            // logical col-group
    int r6    = r & 63;
    int ntile = r >> 6;
    int ss    = sg ^ (r6 & 7);                           // swizzled slot
    size_t op = ((((size_t)jj * 32 + ntile) * 32 + ktile) << 12)
              + ((size_t)r6 << 6) + ((size_t)ss << 3);
    floatx4 w0 = *(const floatx4*)(W + e);
    floatx4 w1 = *(const floatx4*)(W + e + 4);
    floatx4 m0 = *(const floatx4*)(M + e);
    floatx4 m1 = *(const floatx4*)(M + e + 4);
    bf16x8 o;
    o[0] = (bf16)(w0[0] * m0[0]); o[1] = (bf16)(w0[1] * m0[1]);
    o[2] = (bf16)(w0[2] * m0[2]); o[3] = (bf16)(w0[3] * m0[3]);
    o[4] = (bf16)(w1[0] * m1[0]); o[5] = (bf16)(w1[1] * m1[1]);
    o[6] = (bf16)(w1[2] * m1[2]); o[7] = (bf16)(w1[3] * m1[3]);
    *(bf16x8*)(WMb + op) = o;
}

// ---------------------------------------------------------------------------
// Input-layer GEMM (both operands bf16): 128x128 tile, BK=32, z K-chunks.
// ---------------------------------------------------------------------------
__global__ __launch_bounds__(256, 2)
void gemm_kernel(const bf16* __restrict__ A, int lda,
                 const bf16* __restrict__ Bm, int ldb,
                 float* __restrict__ partial,
                 int chunkK, int Ktot)
{
    __shared__ bf16 As[128 * 32];
    __shared__ bf16 Bs[128 * 32];

    const int t    = threadIdx.x;
    const int lane = t & 63, wave = t >> 6;
    const int wm   = (wave & 1) * 64, wn = (wave >> 1) * 64;
    const int l15  = lane & 15, quad = lane >> 4;
    const int n0   = blockIdx.x * 128, m0 = blockIdx.y * 128;
    const int s    = blockIdx.z;
    const int kb   = s * chunkK;
    const int ke   = (kb + chunkK < Ktot) ? (kb + chunkK) : Ktot;

    const int rA = wave * 16 + (lane >> 2);
    const int cA = (lane & 3) * 8;
    const bf16* pA0 = A  + (size_t)(m0 + rA) * lda + cA + kb;
    const bf16* pA1 = pA0 + (size_t)64 * lda;
    const bf16* pB0 = Bm + (size_t)(n0 + rA) * ldb + cA + kb;
    const bf16* pB1 = pB0 + (size_t)64 * ldb;
    bf16* dA0 = &As[wave * 512];  bf16* dA1 = &As[(wave + 4) * 512];
    bf16* dB0 = &Bs[wave * 512];  bf16* dB1 = &Bs[(wave + 4) * 512];

    floatx4 acc[4][4];
#pragma unroll
    for (int a = 0; a < 4; a++)
#pragma unroll
        for (int b = 0; b < 4; b++) acc[a][b] = (floatx4){0.f, 0.f, 0.f, 0.f};

    for (int k0 = kb; k0 < ke; k0 += 32) {
        __syncthreads();
        load_lds16(pA0, dA0);  load_lds16(pA1, dA1);
        load_lds16(pB0, dB0);  load_lds16(pB1, dB1);
        pA0 += 32; pA1 += 32; pB0 += 32; pB1 += 32;
        __syncthreads();

        bf16x8 af[4], bfr[4];
#pragma unroll
        for (int a = 0; a < 4; a++)
            af[a] = *(const bf16x8*)(&As[(wm + a * 16 + l15) * 32 + quad * 8]);
#pragma unroll
        for (int b = 0; b < 4; b++)
            bfr[b] = *(const bf16x8*)(&Bs[(wn + b * 16 + l15) * 32 + quad * 8]);
#pragma unroll
        for (int a = 0; a < 4; a++)
#pragma unroll
            for (int b = 0; b < 4; b++)
                acc[a][b] = __builtin_amdgcn_mfma_f32_16x16x32_bf16(af[a], bfr[b], acc[a][b], 0, 0, 0);
    }

    float* outp = partial + (size_t)s * (B_SZ * N_SZ);
#pragma unroll
    for (int a = 0; a < 4; a++)
#pragma unroll
        for (int b = 0; b < 4; b++)
#pragma unroll
            for (int r = 0; r < 4; r++) {
                int row = m0 + wm + a * 16 + quad * 4 + r;
                int col = n0 + wn + b * 16 + l15;
                outp[(size_t)row * N_SZ + col] = acc[a][b][r];
            }
}

// ---------------------------------------------------------------------------
// DAG GEMM v3: consumes PRE-PACKED bf16 WMb tiles (swizzle baked in by
// wm_pack). M-tile 512 (full batch), N-tile 64, 8 waves, BK=64.
//  - B stage: 1 bf16x8 global read/thread/tile (8KB contiguous per block),
//    2-tile-deep reg prefetch (ga/gb), linear conflict-free ds_write.
//  - A frags: issued one tile EARLY into double-buffered regs (af0/af1) so
//    the acquire-fence barrier no longer exposes L2 latency per iteration.
//  - one barrier per 64-k tile; z = blockIdx&7 keeps A L2-local per XCD.
// Numerics identical to v2 (same bf16(W*M) values, same MFMA order).
// ---------------------------------------------------------------------------
__global__ __launch_bounds__(512, 2)
void dag_gemm_kernel(const bf16* __restrict__ A,
                     const bf16* __restrict__ WMb,   // [jj][ntile][ktile][4096]
                     float* __restrict__ partial,
                     int chunkK)
{
    __shared__ bf16 Bs[2][4096];                 // 8 KB x2

    const int t    = threadIdx.x;
    const int lane = t & 63, wave = t >> 6;      // wave owns rows wave*64..+63
    const int l15  = lane & 15, quad = lane >> 4;
    const int ntile = blockIdx.x >> 3;           // 32 col-tiles
    const int z    = blockIdx.x & 7;             // K-chunk == XCD slot
    const int kb   = z * chunkK;
    const int nt   = chunkK >> 6;                // 4*i tiles, >= 4, even
    const int tile0 = kb >> 6;                   // global ktile of tile 0

    const bf16* Abase = A + (size_t)(wave * 64 + l15) * ACT_LD + quad * 8 + kb;

    floatx4 acc[4][4];
#pragma unroll
    for (int a = 0; a < 4; a++)
#pragma unroll
        for (int b = 0; b < 4; b++) acc[a][b] = (floatx4){0.f, 0.f, 0.f, 0.f};

    bf16x8 ga, gb;                               // staged WM tile regs
    bf16x8 af0[8], af1[8];                       // A frags, even/odd tile

    auto loadWM = [&](bf16x8& g, int tt) {
        int gt = tile0 + tt;
        size_t off = ((((size_t)(gt >> 5) * 32 + ntile) * 32 + (gt & 31)) << 12)
                   + ((size_t)t << 3);
        g = *(const bf16x8*)(WMb + off);
    };
    auto loadA = [&](bf16x8* af, int tt) {
        const bf16* ap = Abase + tt * 64;
#pragma unroll
        for (int a = 0; a < 4; a++) {
            af[a]     = *(const bf16x8*)(ap + (size_t)(a * 16) * ACT_LD);
            af[4 + a] = *(const bf16x8*)(ap + (size_t)(a * 16) * ACT_LD + 32);
        }
    };
    auto commit = [&](int buf, const bf16x8& g) {
        *(bf16x8*)(&Bs[buf][t << 3]) = g;        // linear: conflict-free
    };
    auto mma = [&](int buf, const bf16x8* af) {
#pragma unroll
        for (int kk = 0; kk < 2; kk++) {
            const int e = (kk * 32 + quad * 8) ^ ((l15 & 7) << 3);
            bf16x8 bfr[4];
#pragma unroll
            for (int b = 0; b < 4; b++)
                bfr[b] = *(const bf16x8*)(&Bs[buf][(b * 16 + l15) * 64 + e]);
#pragma unroll
            for (int a = 0; a < 4; a++)
#pragma unroll
                for (int b = 0; b < 4; b++)
                    acc[a][b] = __builtin_amdgcn_mfma_f32_16x16x32_bf16(
                        af[kk * 4 + a], bfr[b], acc[a][b], 0, 0, 0);
        }
    };

    // prologue (nt >= 4 always): ga<-tile0, gb<-tile1, af0<-tile0;
    // commit tile0; ga<-tile2; af1<-tile1.
    loadWM(ga, 0);
    loadWM(gb, 1);
    loadA(af0, 0);
    commit(0, ga);
    loadWM(ga, 2);
    loadA(af1, 1);
    __syncthreads();

    for (int tt = 0; tt < nt; tt += 2) {
        // even iter tt: compute buf0 (tile tt); commit gb=tile tt+1 -> buf1
        commit(1, gb);
        if (tt + 3 < nt) loadWM(gb, tt + 3);
        mma(0, af0);
        if (tt + 2 < nt) loadA(af0, tt + 2);
        __syncthreads();
        // odd iter tt+1: compute buf1 (tile tt+1); commit ga=tile tt+2 -> buf0
        if (tt + 2 < nt) commit(0, ga);
        if (tt + 4 < nt) loadWM(ga, tt + 4);
        mma(1, af1);
        if (tt + 3 < nt) loadA(af1, tt + 3);
        __syncthreads();
    }

    // C/D layout: col = lane&15, row = quad*4 + reg
    float* outp = partial + (size_t)z * (B_SZ * N_SZ);
#pragma unroll
    for (int a = 0; a < 4; a++)
#pragma unroll
        for (int b = 0; b < 4; b++)
#pragma unroll
            for (int r = 0; r < 4; r++) {
                int row = wave * 64 + a * 16 + quad * 4 + r;
                int col = ntile * 64 + b * 16 + l15;
                outp[(size_t)row * N_SZ + col] = acc[a][b][r];
            }
}

// ---------------------------------------------------------------------------
// epilogue: actsT[b][slice*2048+n] = bf16(relu(sum_s partial[s][b][n] + bscale*bias[n]))
// ---------------------------------------------------------------------------
__global__ __launch_bounds__(256)
void epilogue_kernel(const float* __restrict__ partial, int S,
                     const float* __restrict__ bias, float bscale,
                     bf16* __restrict__ actdst)   // = actsT + slice*2048
{
    int g = blockIdx.x * 256 + threadIdx.x;       // 262144 groups of 4
    size_t off = (size_t)g * 4;
    int b = (int)(off >> 11);
    int n = (int)(off & (N_SZ - 1));
    floatx4 v = *(const floatx4*)(partial + off);
    for (int s2 = 1; s2 < S; s2++)
        v += *(const floatx4*)(partial + (size_t)s2 * (B_SZ * N_SZ) + off);
    floatx4 bv = *(const floatx4*)(bias + n);
    bf16x4 o;
#pragma unroll
    for (int j = 0; j < 4; j++) {
        float xv = v[j] + bscale * bv[j];
        xv = xv > 0.f ? xv : 0.f;
        o[j] = (bf16)xv;
    }
    *(bf16x4*)(actdst + (size_t)b * ACT_LD + n) = o;
}

// ---------------------------------------------------------------------------
// output: out[b,c] = act5[b]·w1[c] + b1[c] + act4[b]·w2[c] + b2[c]
// ---------------------------------------------------------------------------
__global__ __launch_bounds__(64)
void out_kernel(const bf16* __restrict__ act4, const bf16* __restrict__ act5,
                const float* __restrict__ w1, const float* __restrict__ b1,
                const float* __restrict__ w2, const float* __restrict__ b2,
                float* __restrict__ out)
{
    int b = blockIdx.x, lane = threadIdx.x;
    float a5[32], a4[32];
#pragma unroll
    for (int rep = 0; rep < 4; rep++) {
        bf16x8 v5 = *(const bf16x8*)(act5 + (size_t)b * ACT_LD + rep * 512 + lane * 8);
        bf16x8 v4 = *(const bf16x8*)(act4 + (size_t)b * ACT_LD + rep * 512 + lane * 8);
#pragma unroll
        for (int j = 0; j < 8; j++) {
            a5[rep * 8 + j] = (float)v5[j];
            a4[rep * 8 + j] = (float)v4[j];
        }
    }
    for (int c = 0; c < 10; c++) {
        float d = 0.f;
#pragma unroll
        for (int rep = 0; rep < 4; rep++) {
            floatx4 wa = *(const floatx4*)(w1 + (size_t)c * N_SZ + rep * 512 + lane * 8);
            floatx4 wb = *(const floatx4*)(w1 + (size_t)c * N_SZ + rep * 512 + lane * 8 + 4);
            floatx4 va = *(const floatx4*)(w2 + (size_t)c * N_SZ + rep * 512 + lane * 8);
            floatx4 vb = *(const floatx4*)(w2 + (size_t)c * N_SZ + rep * 512 + lane * 8 + 4);
#pragma unroll
            for (int j = 0; j < 4; j++) {
                d += a5[rep * 8 + j] * wa[j] + a4[rep * 8 + j] * va[j];
                d += a5[rep * 8 + 4 + j] * wb[j] + a4[rep * 8 + 4 + j] * vb[j];
            }
        }
        for (int off = 32; off > 0; off >>= 1) d += __shfl_down(d, off);
        if (lane == 0) out[b * 10 + c] = d + b1[c] + b2[c];
    }
}

// ---------------------------------------------------------------------------
extern "C" void kernel_launch(void* const* d_in, const int* in_sizes, int n_in,
                              void* d_out, int out_size, void* d_ws, size_t ws_size,
                              hipStream_t stream)
{
    const float* x    = (const float*)d_in[0];
    const float* w_in = (const float*)d_in[1];
    const float* b_in = (const float*)d_in[2];
    const float* W    = (const float*)d_in[3];
    const float* M    = (const float*)d_in[4];
    const float* bL   = (const float*)d_in[5];
    const float* w1   = (const float*)d_in[6];
    const float* b1   = (const float*)d_in[7];
    const float* w2   = (const float*)d_in[8];
    const float* b2   = (const float*)d_in[9];
    float* out = (float*)d_out;

    // workspace layout (all 16B-aligned):
    //   xb     @ 0        : 512*800*2     =    819200
    //   w_inb  @ 819200   : 2048*800*2    =   3276800
    //   actsT  @ 4096000  : 512*12288*2   =  12582912
    //   partial@ 16678912 : 8*512*2048*4  =  33554432
    //   WMb    @ 50233344 : 15*4M*2       = 125829120   (end ~176 MB)
    char* ws = (char*)d_ws;
    bf16*  xb      = (bf16*)ws;
    bf16*  w_inb   = (bf16*)(ws + 819200);
    bf16*  actsT   = (bf16*)(ws + 4096000);
    float* partial = (float*)(ws + 16678912);
    bf16*  WMb     = (bf16*)(ws + 50233344);

    prep_kernel<<<2000, 256, 0, stream>>>(x, w_in, xb, w_inb);

    // pack all 15 W*M matrices -> tiled swizzled bf16 (the only fp32 W/M pass)
    wm_pack_kernel<<<30720, 256, 0, stream>>>(W, M, WMb);

    // input layer: A=xb [512x800], B=w_inb [2048x800], z=4 chunks of 224
    gemm_kernel<<<dim3(16, 4, 4), 256, 0, stream>>>(
        xb, DINP, w_inb, DINP, partial, 224, DINP);
    epilogue_kernel<<<1024, 256, 0, stream>>>(partial, 4, b_in, 1.0f, actsT);

    // DAG layers: 256 blocks x 512 threads; z = blockIdx&7 (XCD-local A)
    for (int i = 1; i < 6; i++) {
        int idx = i * (i - 1) / 2;
        const bf16* WMl = WMb + ((size_t)idx << 22);   // 4M elems per matrix
        dag_gemm_kernel<<<256, 512, 0, stream>>>(
            actsT, WMl, partial, 256 * i);
        epilogue_kernel<<<1024, 256, 0, stream>>>(
            partial, 8, bL + (size_t)(i - 1) * N_SZ, (float)i,
            actsT + (size_t)i * N_SZ);
    }

    out_kernel<<<512, 64, 0, stream>>>(
        actsT + (size_t)4 * N_SZ, actsT + (size_t)5 * N_SZ,
        w1, b1, w2, b2, out);
}

// Round 8
// 641.716 us; speedup vs baseline: 1.1561x; 1.1561x over previous
//
#include <hip/hip_runtime.h>

typedef __bf16 bf16;
typedef __attribute__((ext_vector_type(8))) __bf16 bf16x8;
typedef __attribute__((ext_vector_type(4))) __bf16 bf16x4;
typedef __attribute__((ext_vector_type(4))) float floatx4;

#define B_SZ 512
#define N_SZ 2048
#define DIN  784
#define DINP 800      // 784 padded to multiple of 32
#define ACT_LD 12288  // actsT row stride: 6 slices x 2048

// async global->LDS, 16B per lane (input-layer gemm only)
__device__ __forceinline__ void load_lds16(const bf16* g, bf16* l) {
    __builtin_amdgcn_global_load_lds(
        (const __attribute__((address_space(1))) void*)g,
        (__attribute__((address_space(3))) void*)l, 16, 0, 0);
}

// ---------------------------------------------------------------------------
// prep: x[512][784] -> xb[512][800] bf16 (zero pad), w_in[2048][784] -> w_inb
// ---------------------------------------------------------------------------
__global__ __launch_bounds__(256)
void prep_kernel(const float* __restrict__ x, const float* __restrict__ w_in,
                 bf16* __restrict__ xb, bf16* __restrict__ w_inb)
{
    int g = blockIdx.x * 256 + threadIdx.x;
    const int GPR = DINP / 4;                         // 200 groups per row
    const float* src; bf16* dst; int row, c;
    if (g < B_SZ * GPR) {
        row = g / GPR; c = g - row * GPR;
        src = x + (size_t)row * DIN;  dst = xb + (size_t)row * DINP;
    } else {
        int h = g - B_SZ * GPR;
        row = h / GPR; c = h - row * GPR;
        src = w_in + (size_t)row * DIN;  dst = w_inb + (size_t)row * DINP;
    }
    int k = c * 4;
    floatx4 v = (floatx4){0.f, 0.f, 0.f, 0.f};
    if (k < DIN) v = *(const floatx4*)(src + k);      // 784 % 4 == 0
    bf16x4 o;
    o[0] = (bf16)v[0]; o[1] = (bf16)v[1]; o[2] = (bf16)v[2]; o[3] = (bf16)v[3];
    *(bf16x4*)(dst + k) = o;
}

// ---------------------------------------------------------------------------
// Input-layer GEMM (both operands bf16): 128x128 tile, BK=32, z K-chunks.
// ---------------------------------------------------------------------------
__global__ __launch_bounds__(256, 2)
void gemm_kernel(const bf16* __restrict__ A, int lda,
                 const bf16* __restrict__ Bm, int ldb,
                 float* __restrict__ partial,
                 int chunkK, int Ktot)
{
    __shared__ bf16 As[128 * 32];
    __shared__ bf16 Bs[128 * 32];

    const int t    = threadIdx.x;
    const int lane = t & 63, wave = t >> 6;
    const int wm   = (wave & 1) * 64, wn = (wave >> 1) * 64;
    const int l15  = lane & 15, quad = lane >> 4;
    const int n0   = blockIdx.x * 128, m0 = blockIdx.y * 128;
    const int s    = blockIdx.z;
    const int kb   = s * chunkK;
    const int ke   = (kb + chunkK < Ktot) ? (kb + chunkK) : Ktot;

    const int rA = wave * 16 + (lane >> 2);
    const int cA = (lane & 3) * 8;
    const bf16* pA0 = A  + (size_t)(m0 + rA) * lda + cA + kb;
    const bf16* pA1 = pA0 + (size_t)64 * lda;
    const bf16* pB0 = Bm + (size_t)(n0 + rA) * ldb + cA + kb;
    const bf16* pB1 = pB0 + (size_t)64 * ldb;
    bf16* dA0 = &As[wave * 512];  bf16* dA1 = &As[(wave + 4) * 512];
    bf16* dB0 = &Bs[wave * 512];  bf16* dB1 = &Bs[(wave + 4) * 512];

    floatx4 acc[4][4];
#pragma unroll
    for (int a = 0; a < 4; a++)
#pragma unroll
        for (int b = 0; b < 4; b++) acc[a][b] = (floatx4){0.f, 0.f, 0.f, 0.f};

    for (int k0 = kb; k0 < ke; k0 += 32) {
        __syncthreads();
        load_lds16(pA0, dA0);  load_lds16(pA1, dA1);
        load_lds16(pB0, dB0);  load_lds16(pB1, dB1);
        pA0 += 32; pA1 += 32; pB0 += 32; pB1 += 32;
        __syncthreads();

        bf16x8 af[4], bfr[4];
#pragma unroll
        for (int a = 0; a < 4; a++)
            af[a] = *(const bf16x8*)(&As[(wm + a * 16 + l15) * 32 + quad * 8]);
#pragma unroll
        for (int b = 0; b < 4; b++)
            bfr[b] = *(const bf16x8*)(&Bs[(wn + b * 16 + l15) * 32 + quad * 8]);
#pragma unroll
        for (int a = 0; a < 4; a++)
#pragma unroll
            for (int b = 0; b < 4; b++)
                acc[a][b] = __builtin_amdgcn_mfma_f32_16x16x32_bf16(af[a], bfr[b], acc[a][b], 0, 0, 0);
    }

    float* outp = partial + (size_t)s * (B_SZ * N_SZ);
#pragma unroll
    for (int a = 0; a < 4; a++)
#pragma unroll
        for (int b = 0; b < 4; b++)
#pragma unroll
            for (int r = 0; r < 4; r++) {
                int row = m0 + wm + a * 16 + quad * 4 + r;
                int col = n0 + wn + b * 16 + l15;
                outp[(size_t)row * N_SZ + col] = acc[a][b][r];
            }
}

// ---------------------------------------------------------------------------
// DAG GEMM v4: fused fp32 W/M read (NO pack prepass — packing's 126MB write
// + 120MB re-read + 166us dispatch can never beat fused conversion).
// M-tile 512 (full batch), N-tile 64, 8 waves, BK=64, double-buffered LDS.
//  - W/M: 2-tile-deep register prefetch; bf16(W*M) packed in-reg at commit,
//    XOR-swizzled ds_write (conflict-free; same swizzle on read).
//  - A frags: double-buffered registers (af0/af1), loaded one tile early.
//  - KEY CHANGE vs v2: raw s_barrier + lgkmcnt(0) only — NOT __syncthreads().
//    __syncthreads emits s_waitcnt vmcnt(0) which drains ALL in-flight
//    global loads at every barrier, nullifying the prefetch. Our global
//    loads target REGISTERS only (no LDS DMA), so no vmcnt drain is needed
//    for correctness: the compiler emits exact counted vmcnt(N) before each
//    register consumer. Loads now stay in flight across barriers (T4-lite).
//  - z = blockIdx&7 -> K-chunk pinned to one XCD (A reads L2-local).
// Numerics identical to v2 (same pack math, same MFMA order, z=8 partials).
// ---------------------------------------------------------------------------
__global__ __launch_bounds__(512, 2)
void dag_gemm_kernel(const bf16* __restrict__ A,
                     const float* __restrict__ Wl, const float* __restrict__ Ml,
                     float* __restrict__ partial,
                     int chunkK)
{
    __shared__ bf16 Bs[2][4096];                 // 8 KB x2

    const int t    = threadIdx.x;
    const int lane = t & 63, wave = t >> 6;      // wave owns rows wave*64..+63
    const int l15  = lane & 15, quad = lane >> 4;
    const int n0   = (blockIdx.x >> 3) * 64;     // 32 col-tiles
    const int z    = blockIdx.x & 7;             // K-chunk == XCD slot
    const int kb   = z * chunkK;
    const int nt   = chunkK >> 6;                // 4*i tiles, >= 4, even

    // W/M staging: thread covers W row n0+br, k-seg bc..bc+7 (8 fp32 = 32B)
    const int br = t >> 3, bc = (t & 7) * 8;
    const size_t wrow = (size_t)(n0 + br) << 11;
    bf16* bdst = &Bs[0][br * 64 + (bc ^ ((br & 7) << 3))];

    const bf16* Abase = A + (size_t)(wave * 64 + l15) * ACT_LD + quad * 8 + kb;

    floatx4 acc[4][4];
#pragma unroll
    for (int a = 0; a < 4; a++)
#pragma unroll
        for (int b = 0; b < 4; b++) acc[a][b] = (floatx4){0.f, 0.f, 0.f, 0.f};

    // prefetch register stages
    floatx4 w0a, w1a, m0a, m1a;                  // WM stage A (even tiles)
    floatx4 w0b, w1b, m0b, m1b;                  // WM stage B (odd tiles)
    bf16x8 af0[8], af1[8];                       // A frags, even/odd tile

#define LOAD_WM(tt, w0, w1, m0, m1) do {                          \
        int k = kb + (tt) * 64;                                   \
        int jj = k >> 11, kk2 = k & 2047;                         \
        size_t o = ((size_t)jj << 22) + wrow + kk2 + bc;          \
        w0 = *(const floatx4*)(Wl + o);                           \
        w1 = *(const floatx4*)(Wl + o + 4);                       \
        m0 = *(const floatx4*)(Ml + o);                           \
        m1 = *(const floatx4*)(Ml + o + 4);                       \
    } while (0)

#define COMMIT(buf, w0, w1, m0, m1) do {                          \
        bf16x8 o8;                                                \
        o8[0] = (bf16)(w0[0] * m0[0]); o8[1] = (bf16)(w0[1] * m0[1]); \
        o8[2] = (bf16)(w0[2] * m0[2]); o8[3] = (bf16)(w0[3] * m0[3]); \
        o8[4] = (bf16)(w1[0] * m1[0]); o8[5] = (bf16)(w1[1] * m1[1]); \
        o8[6] = (bf16)(w1[2] * m1[2]); o8[7] = (bf16)(w1[3] * m1[3]); \
        *(bf16x8*)(bdst + (buf) * 4096) = o8;                     \
    } while (0)

    // barrier WITHOUT vmcnt drain: ds ops must be visible (lgkmcnt 0), but
    // in-flight global loads (register targets) survive the barrier.
#define BAR() do {                                                \
        asm volatile("s_waitcnt lgkmcnt(0)" ::: "memory");        \
        __builtin_amdgcn_s_barrier();                             \
    } while (0)

    auto loadA = [&](bf16x8* af, int tt) {
        const bf16* ap = Abase + tt * 64;
#pragma unroll
        for (int a = 0; a < 4; a++) {
            af[a]     = *(const bf16x8*)(ap + (size_t)(a * 16) * ACT_LD);
            af[4 + a] = *(const bf16x8*)(ap + (size_t)(a * 16) * ACT_LD + 32);
        }
    };
    auto mma = [&](int buf, const bf16x8* af) {
#pragma unroll
        for (int kk = 0; kk < 2; kk++) {
            const int e = (kk * 32 + quad * 8) ^ ((l15 & 7) << 3);
            bf16x8 bfr[4];
#pragma unroll
            for (int b = 0; b < 4; b++)
                bfr[b] = *(const bf16x8*)(&Bs[buf][(b * 16 + l15) * 64 + e]);
#pragma unroll
            for (int a = 0; a < 4; a++)
#pragma unroll
                for (int b = 0; b < 4; b++)
                    acc[a][b] = __builtin_amdgcn_mfma_f32_16x16x32_bf16(
                        af[kk * 4 + a], bfr[b], acc[a][b], 0, 0, 0);
        }
    };

    // prologue (nt >= 4): stageA<-tile0, stageB<-tile1, af0<-tile0;
    // commit tile0; stageA<-tile2; af1<-tile1.
    LOAD_WM(0, w0a, w1a, m0a, m1a);
    LOAD_WM(1, w0b, w1b, m0b, m1b);
    loadA(af0, 0);
    COMMIT(0, w0a, w1a, m0a, m1a);
    LOAD_WM(2, w0a, w1a, m0a, m1a);
    loadA(af1, 1);
    BAR();

    for (int tt = 0; tt < nt; tt += 2) {
        // even iter tt: commit WM(tt+1)->buf1; compute buf0 (tile tt)
        COMMIT(1, w0b, w1b, m0b, m1b);
        if (tt + 3 < nt) LOAD_WM(tt + 3, w0b, w1b, m0b, m1b);
        mma(0, af0);
        if (tt + 2 < nt) loadA(af0, tt + 2);
        BAR();
        // odd iter tt+1: commit WM(tt+2)->buf0; compute buf1 (tile tt+1)
        if (tt + 2 < nt) COMMIT(0, w0a, w1a, m0a, m1a);
        if (tt + 4 < nt) LOAD_WM(tt + 4, w0a, w1a, m0a, m1a);
        mma(1, af1);
        if (tt + 3 < nt) loadA(af1, tt + 3);
        BAR();
    }
#undef LOAD_WM
#undef COMMIT
#undef BAR

    // C/D layout: col = lane&15, row = quad*4 + reg
    float* outp = partial + (size_t)z * (B_SZ * N_SZ);
#pragma unroll
    for (int a = 0; a < 4; a++)
#pragma unroll
        for (int b = 0; b < 4; b++)
#pragma unroll
            for (int r = 0; r < 4; r++) {
                int row = wave * 64 + a * 16 + quad * 4 + r;
                int col = n0 + b * 16 + l15;
                outp[(size_t)row * N_SZ + col] = acc[a][b][r];
            }
}

// ---------------------------------------------------------------------------
// epilogue: actsT[b][slice*2048+n] = bf16(relu(sum_s partial[s][b][n] + bscale*bias[n]))
// ---------------------------------------------------------------------------
__global__ __launch_bounds__(256)
void epilogue_kernel(const float* __restrict__ partial, int S,
                     const float* __restrict__ bias, float bscale,
                     bf16* __restrict__ actdst)   // = actsT + slice*2048
{
    int g = blockIdx.x * 256 + threadIdx.x;       // 262144 groups of 4
    size_t off = (size_t)g * 4;
    int b = (int)(off >> 11);
    int n = (int)(off & (N_SZ - 1));
    floatx4 v = *(const floatx4*)(partial + off);
    for (int s2 = 1; s2 < S; s2++)
        v += *(const floatx4*)(partial + (size_t)s2 * (B_SZ * N_SZ) + off);
    floatx4 bv = *(const floatx4*)(bias + n);
    bf16x4 o;
#pragma unroll
    for (int j = 0; j < 4; j++) {
        float xv = v[j] + bscale * bv[j];
        xv = xv > 0.f ? xv : 0.f;
        o[j] = (bf16)xv;
    }
    *(bf16x4*)(actdst + (size_t)b * ACT_LD + n) = o;
}

// ---------------------------------------------------------------------------
// output: out[b,c] = act5[b]·w1[c] + b1[c] + act4[b]·w2[c] + b2[c]
// ---------------------------------------------------------------------------
__global__ __launch_bounds__(64)
void out_kernel(const bf16* __restrict__ act4, const bf16* __restrict__ act5,
                const float* __restrict__ w1, const float* __restrict__ b1,
                const float* __restrict__ w2, const float* __restrict__ b2,
                float* __restrict__ out)
{
    int b = blockIdx.x, lane = threadIdx.x;
    float a5[32], a4[32];
#pragma unroll
    for (int rep = 0; rep < 4; rep++) {
        bf16x8 v5 = *(const bf16x8*)(act5 + (size_t)b * ACT_LD + rep * 512 + lane * 8);
        bf16x8 v4 = *(const bf16x8*)(act4 + (size_t)b * ACT_LD + rep * 512 + lane * 8);
#pragma unroll
        for (int j = 0; j < 8; j++) {
            a5[rep * 8 + j] = (float)v5[j];
            a4[rep * 8 + j] = (float)v4[j];
        }
    }
    for (int c = 0; c < 10; c++) {
        float d = 0.f;
#pragma unroll
        for (int rep = 0; rep < 4; rep++) {
            floatx4 wa = *(const floatx4*)(w1 + (size_t)c * N_SZ + rep * 512 + lane * 8);
            floatx4 wb = *(const floatx4*)(w1 + (size_t)c * N_SZ + rep * 512 + lane * 8 + 4);
            floatx4 va = *(const floatx4*)(w2 + (size_t)c * N_SZ + rep * 512 + lane * 8);
            floatx4 vb = *(const floatx4*)(w2 + (size_t)c * N_SZ + rep * 512 + lane * 8 + 4);
#pragma unroll
            for (int j = 0; j < 4; j++) {
                d += a5[rep * 8 + j] * wa[j] + a4[rep * 8 + j] * va[j];
                d += a5[rep * 8 + 4 + j] * wb[j] + a4[rep * 8 + 4 + j] * vb[j];
            }
        }
        for (int off = 32; off > 0; off >>= 1) d += __shfl_down(d, off);
        if (lane == 0) out[b * 10 + c] = d + b1[c] + b2[c];
    }
}

// ---------------------------------------------------------------------------
extern "C" void kernel_launch(void* const* d_in, const int* in_sizes, int n_in,
                              void* d_out, int out_size, void* d_ws, size_t ws_size,
                              hipStream_t stream)
{
    const float* x    = (const float*)d_in[0];
    const float* w_in = (const float*)d_in[1];
    const float* b_in = (const float*)d_in[2];
    const float* W    = (const float*)d_in[3];
    const float* M    = (const float*)d_in[4];
    const float* bL   = (const float*)d_in[5];
    const float* w1   = (const float*)d_in[6];
    const float* b1   = (const float*)d_in[7];
    const float* w2   = (const float*)d_in[8];
    const float* b2   = (const float*)d_in[9];
    float* out = (float*)d_out;

    // workspace layout (all 16B-aligned):
    //   xb     @ 0        : 512*800*2    =    819200
    //   w_inb  @ 819200   : 2048*800*2   =   3276800
    //   actsT  @ 4096000  : 512*12288*2  =  12582912
    //   partial@ 16678912 : 8*512*2048*4 =  33554432   (end ~50 MB)
    char* ws = (char*)d_ws;
    bf16*  xb      = (bf16*)ws;
    bf16*  w_inb   = (bf16*)(ws + 819200);
    bf16*  actsT   = (bf16*)(ws + 4096000);
    float* partial = (float*)(ws + 16678912);

    prep_kernel<<<2000, 256, 0, stream>>>(x, w_in, xb, w_inb);

    // input layer: A=xb [512x800], B=w_inb [2048x800], z=4 chunks of 224
    gemm_kernel<<<dim3(16, 4, 4), 256, 0, stream>>>(
        xb, DINP, w_inb, DINP, partial, 224, DINP);
    epilogue_kernel<<<1024, 256, 0, stream>>>(partial, 4, b_in, 1.0f, actsT);

    // DAG layers: fused fp32 W*M; 256 blocks x 512 threads; z = blockIdx&7
    for (int i = 1; i < 6; i++) {
        int idx = i * (i - 1) / 2;
        const float* Wl = W + ((size_t)idx << 22);
        const float* Ml = M + ((size_t)idx << 22);
        dag_gemm_kernel<<<256, 512, 0, stream>>>(
            actsT, Wl, Ml, partial, 256 * i);
        epilogue_kernel<<<1024, 256, 0, stream>>>(
            partial, 8, bL + (size_t)(i - 1) * N_SZ, (float)i,
            actsT + (size_t)i * N_SZ);
    }

    out_kernel<<<512, 64, 0, stream>>>(
        actsT + (size_t)4 * N_SZ, actsT + (size_t)5 * N_SZ,
        w1, b1, w2, b2, out);
}